// Round 1
// baseline (792.853 us; speedup 1.0000x reference)
//
#include <hip/hip_runtime.h>

// ---------------------------------------------------------------------------
// Predictor: per-patch edge classification + global class-mean fixup.
//   phase1: per-patch out in {0,1,2}, center value; reduce sumB/sumW/cntB/cntW
//   phase2: replace out==2 by nearest-class-mean decision (f64, np semantics)
// ---------------------------------------------------------------------------

struct Acc { double sumB; double sumW; unsigned int cntB; unsigned int cntW; };

#define PPB 256  // patches per block (== blockDim.x)

__global__ __launch_bounds__(256) void phase1(const float* __restrict__ img,
                                              const float* __restrict__ edg,
                                              float* __restrict__ out,
                                              Acc* __restrict__ acc)
{
    __shared__ float s_img[PPB * 9];
    __shared__ float s_edg[PPB * 9];
    const int t = threadIdx.x;
    const size_t base = (size_t)blockIdx.x * (PPB * 9);

    // coalesced float4 staging: 576 float4 per array per block
    const float4* gi = reinterpret_cast<const float4*>(img + base);
    const float4* ge = reinterpret_cast<const float4*>(edg + base);
    float4* si = reinterpret_cast<float4*>(s_img);
    float4* se = reinterpret_cast<float4*>(s_edg);
    si[t]       = gi[t];       se[t]       = ge[t];
    si[t + 256] = gi[t + 256]; se[t + 256] = ge[t + 256];
    if (t < 64) { si[t + 512] = gi[t + 512]; se[t + 512] = ge[t + 512]; }
    __syncthreads();

    const float* ip = s_img + 9 * t;   // stride-9 word reads: 2-way LDS alias, free
    const float* ep = s_edg + 9 * t;

    float xd[9], xa[9];
    int cd = 0, ca = 0;
#pragma unroll
    for (int k = 0; k < 9; ++k) {
        float e = ep[k], v = ip[k];
        bool dis = e > 0.5f;
        bool ac  = (e != 0.0f) && !dis;
        xd[k] = dis ? v : 0.0f;
        xa[k] = ac  ? v : 0.0f;
        cd += dis ? 1 : 0;
        ca += ac  ? 1 : 0;
    }
    // numpy pairwise order for 9-element f32 row sum
    float sd = ((xd[0] + xd[1]) + (xd[2] + xd[3])) + ((xd[4] + xd[5]) + (xd[6] + xd[7]));
    sd += xd[8];
    float sa = ((xa[0] + xa[1]) + (xa[2] + xa[3])) + ((xa[4] + xa[5]) + (xa[6] + xa[7]));
    sa += xa[8];

    // md > ma  <=>  sd/cd' > sa/ca'  <=>  sd*ca' > sa*cd'  (exact in f64:
    // f32 mantissa * int<=9 is exact; distinct small-denominator quotients
    // are separated far beyond f64 ulp, so this equals np's f64-division compare)
    const int cdm = cd > 0 ? cd : 1;
    const int cam = ca > 0 ? ca : 1;
    const bool gt = ((double)sd * (double)cam) > ((double)sa * (double)cdm);
    const float o = (cd > 0 && ca > 0) ? (gt ? 0.0f : 1.0f) : 2.0f;
    const float value = ip[4];  // image[:,1,1]

    out[(size_t)blockIdx.x * PPB + t] = o;

    // ---- block reduction: sums (f32) + counts (exact via ballot) ----
    unsigned long long mb = __ballot(o == 0.0f);
    unsigned long long mw = __ballot(o == 1.0f);
    float vb = (o == 0.0f) ? value : 0.0f;
    float vw = (o == 1.0f) ? value : 0.0f;
#pragma unroll
    for (int off = 32; off > 0; off >>= 1) {
        vb += __shfl_down(vb, off);
        vw += __shfl_down(vw, off);
    }
    __shared__ float rb[4], rw[4];
    __shared__ unsigned int ub[4], uw[4];
    const int wave = t >> 6, lane = t & 63;
    if (lane == 0) {
        rb[wave] = vb; rw[wave] = vw;
        ub[wave] = (unsigned)__popcll(mb);
        uw[wave] = (unsigned)__popcll(mw);
    }
    __syncthreads();
    if (t == 0) {
        float fb = (rb[0] + rb[1]) + (rb[2] + rb[3]);
        float fw = (rw[0] + rw[1]) + (rw[2] + rw[3]);
        unsigned cb = ub[0] + ub[1] + ub[2] + ub[3];
        unsigned cw = uw[0] + uw[1] + uw[2] + uw[3];
        atomicAdd(&acc->sumB, (double)fb);
        atomicAdd(&acc->sumW, (double)fw);
        atomicAdd(&acc->cntB, cb);
        atomicAdd(&acc->cntW, cw);
    }
}

__global__ __launch_bounds__(256) void phase2(const float* __restrict__ img,
                                              float* __restrict__ out,
                                              const Acc* __restrict__ acc,
                                              int n4)
{
    const int i = blockIdx.x * 256 + threadIdx.x;
    if (i >= n4) return;
    float4 v = reinterpret_cast<const float4*>(out)[i];
    if (v.x == 2.0f || v.y == 2.0f || v.z == 2.0f || v.w == 2.0f) {
        const unsigned cb = acc->cntB, cw = acc->cntW;
        const double avgB = acc->sumB / (double)(cb ? cb : 1u);
        const double avgW = acc->sumW / (double)(cw ? cw : 1u);
        float r[4] = {v.x, v.y, v.z, v.w};
#pragma unroll
        for (int j = 0; j < 4; ++j) {
            if (r[j] == 2.0f) {
                const size_t p = (size_t)i * 4 + j;
                const double val = (double)img[p * 9 + 4];
                out[p] = (fabs(val - avgB) < fabs(val - avgW)) ? 0.0f : 1.0f;
            }
        }
    }
}

extern "C" void kernel_launch(void* const* d_in, const int* in_sizes, int n_in,
                              void* d_out, int out_size, void* d_ws, size_t ws_size,
                              hipStream_t stream) {
    const float* img = (const float*)d_in[0];
    const float* edg = (const float*)d_in[1];
    // d_in[2] (gt) only contributes its shape; unused.
    float* out = (float*)d_out;
    Acc* acc = (Acc*)d_ws;

    hipMemsetAsync(d_ws, 0, sizeof(Acc), stream);  // ws poisoned 0xAA; zero every call

    const int N = in_sizes[0] / 9;            // 4194304 patches
    const int blocks1 = N / PPB;              // N divisible by 256
    phase1<<<blocks1, 256, 0, stream>>>(img, edg, out, acc);

    const int n4 = N / 4;
    phase2<<<(n4 + 255) / 256, 256, 0, stream>>>(img, out, acc, n4);
}

// Round 2
// 69.876 us; speedup vs baseline: 11.3467x; 11.3467x over previous
//
#include <hip/hip_runtime.h>

// ---------------------------------------------------------------------------
// Predictor: per-patch edge classification + global class-mean fixup.
//   phase1: per-patch out in {0,1,2}; per-BLOCK partial sums/counts (no atomics)
//   reduceK: 1024 partials -> final Acc (f64), single block
//   phase2: replace out==2 by nearest-class-mean decision (f64, np semantics)
// R1 lesson: 64k same-address atomics serialized at ~30 cy each = 780us.
// ---------------------------------------------------------------------------

struct Partial { float sb, sw; unsigned int cb, cw; };          // 16 B
struct Acc     { double sumB, sumW; unsigned int cntB, cntW; };

#define PPB    256   // patches per chunk (== blockDim.x)
#define CHUNKS 4     // chunks per block
#define NBLK1  4096  // N / (PPB*CHUNKS) for N = 4194304

__global__ __launch_bounds__(256) void phase1(const float* __restrict__ img,
                                              const float* __restrict__ edg,
                                              float* __restrict__ out,
                                              Partial* __restrict__ part)
{
    __shared__ float s_img[PPB * 9];
    __shared__ float s_edg[PPB * 9];
    const int t = threadIdx.x;

    float accB = 0.0f, accW = 0.0f;
    int   ncb = 0, ncw = 0;

    for (int c = 0; c < CHUNKS; ++c) {
        const size_t chunk = (size_t)blockIdx.x * CHUNKS + c;
        const size_t base  = chunk * (PPB * 9);

        // coalesced float4 staging: 576 float4 per array per chunk
        const float4* gi = reinterpret_cast<const float4*>(img + base);
        const float4* ge = reinterpret_cast<const float4*>(edg + base);
        float4* si = reinterpret_cast<float4*>(s_img);
        float4* se = reinterpret_cast<float4*>(s_edg);
        si[t]       = gi[t];       se[t]       = ge[t];
        si[t + 256] = gi[t + 256]; se[t + 256] = ge[t + 256];
        if (t < 64) { si[t + 512] = gi[t + 512]; se[t + 512] = ge[t + 512]; }
        __syncthreads();

        const float* ip = s_img + 9 * t;   // stride-9 word reads: 2-way alias, free
        const float* ep = s_edg + 9 * t;

        float xd[9], xa[9];
        int cd = 0, ca = 0;
#pragma unroll
        for (int k = 0; k < 9; ++k) {
            float e = ep[k], v = ip[k];
            bool dis = e > 0.5f;
            bool ac  = (e != 0.0f) && !dis;
            xd[k] = dis ? v : 0.0f;
            xa[k] = ac  ? v : 0.0f;
            cd += dis ? 1 : 0;
            ca += ac  ? 1 : 0;
        }
        // numpy pairwise order for 9-element f32 row sum
        float sd = ((xd[0] + xd[1]) + (xd[2] + xd[3])) + ((xd[4] + xd[5]) + (xd[6] + xd[7]));
        sd += xd[8];
        float sa = ((xa[0] + xa[1]) + (xa[2] + xa[3])) + ((xa[4] + xa[5]) + (xa[6] + xa[7]));
        sa += xa[8];

        // md > ma  <=>  sd*ca' > sa*cd'  (exact in f64; equals np's f64-div compare)
        const int cdm = cd > 0 ? cd : 1;
        const int cam = ca > 0 ? ca : 1;
        const bool gt = ((double)sd * (double)cam) > ((double)sa * (double)cdm);
        const float o = (cd > 0 && ca > 0) ? (gt ? 0.0f : 1.0f) : 2.0f;
        const float value = ip[4];  // image[:,1,1]

        out[chunk * PPB + t] = o;

        accB += (o == 0.0f) ? value : 0.0f;
        accW += (o == 1.0f) ? value : 0.0f;
        ncb  += (o == 0.0f) ? 1 : 0;
        ncw  += (o == 1.0f) ? 1 : 0;

        __syncthreads();  // LDS reused next chunk
    }

    // ---- block reduction into ONE partial (no global atomics) ----
#pragma unroll
    for (int off = 32; off > 0; off >>= 1) {
        accB += __shfl_down(accB, off);
        accW += __shfl_down(accW, off);
        ncb  += __shfl_down(ncb, off);
        ncw  += __shfl_down(ncw, off);
    }
    __shared__ float rb[4], rw[4];
    __shared__ unsigned int ub[4], uw[4];
    const int wave = t >> 6, lane = t & 63;
    if (lane == 0) { rb[wave] = accB; rw[wave] = accW; ub[wave] = ncb; uw[wave] = ncw; }
    __syncthreads();
    if (t == 0) {
        Partial p;
        p.sb = (rb[0] + rb[1]) + (rb[2] + rb[3]);
        p.sw = (rw[0] + rw[1]) + (rw[2] + rw[3]);
        p.cb = ub[0] + ub[1] + ub[2] + ub[3];
        p.cw = uw[0] + uw[1] + uw[2] + uw[3];
        part[blockIdx.x] = p;
    }
}

__global__ __launch_bounds__(256) void reduceK(const Partial* __restrict__ part,
                                               int n, Acc* __restrict__ acc)
{
    const int t = threadIdx.x;
    double sb = 0.0, sw = 0.0;
    unsigned int cb = 0, cw = 0;
    for (int i = t; i < n; i += 256) {
        Partial p = part[i];
        sb += (double)p.sb; sw += (double)p.sw; cb += p.cb; cw += p.cw;
    }
#pragma unroll
    for (int off = 32; off > 0; off >>= 1) {
        sb += __shfl_down(sb, off);
        sw += __shfl_down(sw, off);
        cb += __shfl_down(cb, off);
        cw += __shfl_down(cw, off);
    }
    __shared__ double db[4], dw[4];
    __shared__ unsigned int eb[4], ew[4];
    const int wave = t >> 6, lane = t & 63;
    if (lane == 0) { db[wave] = sb; dw[wave] = sw; eb[wave] = cb; ew[wave] = cw; }
    __syncthreads();
    if (t == 0) {
        Acc a;
        a.sumB = db[0] + db[1] + db[2] + db[3];
        a.sumW = dw[0] + dw[1] + dw[2] + dw[3];
        a.cntB = eb[0] + eb[1] + eb[2] + eb[3];
        a.cntW = ew[0] + ew[1] + ew[2] + ew[3];
        *acc = a;
    }
}

__global__ __launch_bounds__(256) void phase2(const float* __restrict__ img,
                                              float* __restrict__ out,
                                              const Acc* __restrict__ acc,
                                              int n4)
{
    const int i = blockIdx.x * 256 + threadIdx.x;
    if (i >= n4) return;
    float4 v = reinterpret_cast<const float4*>(out)[i];
    if (v.x == 2.0f || v.y == 2.0f || v.z == 2.0f || v.w == 2.0f) {
        const unsigned cb = acc->cntB, cw = acc->cntW;
        const double avgB = acc->sumB / (double)(cb ? cb : 1u);
        const double avgW = acc->sumW / (double)(cw ? cw : 1u);
        float r[4] = {v.x, v.y, v.z, v.w};
#pragma unroll
        for (int j = 0; j < 4; ++j) {
            if (r[j] == 2.0f) {
                const size_t p = (size_t)i * 4 + j;
                const double val = (double)img[p * 9 + 4];
                out[p] = (fabs(val - avgB) < fabs(val - avgW)) ? 0.0f : 1.0f;
            }
        }
    }
}

extern "C" void kernel_launch(void* const* d_in, const int* in_sizes, int n_in,
                              void* d_out, int out_size, void* d_ws, size_t ws_size,
                              hipStream_t stream) {
    const float* img = (const float*)d_in[0];
    const float* edg = (const float*)d_in[1];
    float* out = (float*)d_out;

    Partial* part = (Partial*)d_ws;                       // 4096 * 16 B = 64 KiB
    Acc*     acc  = (Acc*)((char*)d_ws + NBLK1 * sizeof(Partial));

    const int N = in_sizes[0] / 9;                        // 4194304 patches
    phase1<<<NBLK1, 256, 0, stream>>>(img, edg, out, part);
    reduceK<<<1, 256, 0, stream>>>(part, NBLK1, acc);
    const int n4 = N / 4;
    phase2<<<(n4 + 255) / 256, 256, 0, stream>>>(img, out, acc, n4);
}